// Round 4
// baseline (4220.517 us; speedup 1.0000x reference)
//
#include <hip/hip_runtime.h>
#include <cstdint>
#include <cstddef>

// Problem constants (fixed by reference)
#define N_ROWS  32768
#define DIMS    512
#define K_CODES 8192

// GEMM tiling
#define BM   128
#define BN   128
#define BKD  16
#define SPLITS 2
#define KSPL (K_CODES / SPLITS)   // 4096

// ===========================================================================
// Oracle model (harness "ref=np" transliteration):
//  - normalization + row sum-of-squares: ufunc path -> numpy pairwise
//    summation (SSE baseline: 16 chains per 128-block, combine masks
//    4,8 | 1,2 | 16,32), elementwise sqrt/max/div correctly rounded.
//  - the big N*K dot: BLAS sgemm (xn @ wn.T) -> each C[n,k] is ONE
//    strictly d-ascending fp32 FMA chain starting from 0 (microkernel
//    rank-1 updates; KC panel round-trips don't re-round). This is
//    invariant across OpenBLAS/MKL/AVX width.
//  - distances = fl(fl(xn2 + wn2) - fl(2*dot)); stable argsort ties -> low k.
// ===========================================================================

// 64-lane numpy-pairwise sum of squares of a 512-float LDS row.
// Every lane returns the same value.
__device__ __forceinline__ float np_pairwise_sumsq_512(const float* buf, int l) {
  int blk = l >> 4, jv = (l >> 2) & 3, ln = l & 3;
  int cb = blk * 128 + jv * 4 + ln;
  float v = buf[cb];
  float r = __fmul_rn(v, v);
  #pragma unroll
  for (int i = 1; i < 8; ++i) {
    float t = buf[cb + 16 * i];
    r = __fadd_rn(r, __fmul_rn(t, t));
  }
  r = __fadd_rn(r, __shfl_xor(r, 4, 64));
  r = __fadd_rn(r, __shfl_xor(r, 8, 64));
  r = __fadd_rn(r, __shfl_xor(r, 1, 64));
  r = __fadd_rn(r, __shfl_xor(r, 2, 64));
  r = __fadd_rn(r, __shfl_xor(r, 16, 64));
  r = __fadd_rn(r, __shfl_xor(r, 32, 64));
  return r;
}

// ---------------------------------------------------------------------------
// prep_x: per-row inverse norm of x (fp32) for GEMM on-the-fly normalize.
// (Approximate path: candidates only.)
// ---------------------------------------------------------------------------
__global__ __launch_bounds__(256) void prep_x_kernel(
    const float* __restrict__ x, float* __restrict__ xninv) {
  int row = blockIdx.x * 4 + (threadIdx.x >> 6);
  int l = threadIdx.x & 63;
  const float* xr = x + (size_t)row * DIMS + l * 8;
  float4 a = *(const float4*)xr;
  float4 b = *(const float4*)(xr + 4);
  float s = a.x*a.x + a.y*a.y + a.z*a.z + a.w*a.w
          + b.x*b.x + b.y*b.y + b.z*b.z + b.w*b.w;
  #pragma unroll
  for (int off = 1; off < 64; off <<= 1) s += __shfl_xor(s, off, 64);
  float den = fmaxf(sqrtf(s), 1e-12f);
  if (l == 0) xninv[row] = 1.0f / den;
}

// ---------------------------------------------------------------------------
// prep_w_np: numpy-faithful fp32 normalized codebook + wn2 per row.
// wn feeds both the candidate GEMM and the exact refine scoring.
// ---------------------------------------------------------------------------
__global__ __launch_bounds__(256) void prep_w_np_kernel(
    const float* __restrict__ emb, float* __restrict__ wn,
    float* __restrict__ wnorm2) {
  __shared__ float buf[4][512];
  int w = threadIdx.x >> 6, l = threadIdx.x & 63;
  int row = blockIdx.x * 4 + w;
  const float* wr = emb + (size_t)row * DIMS + l * 8;
  float4 a = *(const float4*)wr;
  float4 b = *(const float4*)(wr + 4);
  *(float4*)&buf[w][l * 8]     = a;
  *(float4*)&buf[w][l * 8 + 4] = b;
  __syncthreads();
  float S = np_pairwise_sumsq_512(buf[w], l);
  float den = fmaxf(__fsqrt_rn(S), 1e-12f);
  float nv[8];
  nv[0] = __fdiv_rn(a.x, den); nv[1] = __fdiv_rn(a.y, den);
  nv[2] = __fdiv_rn(a.z, den); nv[3] = __fdiv_rn(a.w, den);
  nv[4] = __fdiv_rn(b.x, den); nv[5] = __fdiv_rn(b.y, den);
  nv[6] = __fdiv_rn(b.z, den); nv[7] = __fdiv_rn(b.w, den);
  __syncthreads();   // chains done reading raw w before overwrite
  *(float4*)&buf[w][l * 8]     = float4{nv[0], nv[1], nv[2], nv[3]};
  *(float4*)&buf[w][l * 8 + 4] = float4{nv[4], nv[5], nv[6], nv[7]};
  float* wo = wn + (size_t)row * DIMS + l * 8;
  *(float4*)wo       = float4{nv[0], nv[1], nv[2], nv[3]};
  *(float4*)(wo + 4) = float4{nv[4], nv[5], nv[6], nv[7]};
  __syncthreads();
  float S2 = np_pairwise_sumsq_512(buf[w], l);
  if (l == 0) wnorm2[row] = S2;
}

// ---------------------------------------------------------------------------
// gemm_topk: fp32 dot(xn, wn) over a K-split, fused streaming top-4
// candidates per (row, col-parity-stream). Approximate; recall-only.
// ---------------------------------------------------------------------------
#define CAS_INS(TV, TK)                                         \
  { bool sw_ = cv > (TV); float v_ = (TV); int k_ = (TK);       \
    (TV) = sw_ ? cv : (TV); (TK) = sw_ ? ck : (TK);             \
    cv = sw_ ? v_ : cv;     ck = sw_ ? k_ : ck; }

__global__ __launch_bounds__(256) void gemm_topk_kernel(
    const float* __restrict__ x, const float* __restrict__ wn,
    const float* __restrict__ xninv,
    float* __restrict__ candv, int* __restrict__ candi) {
  __shared__ float As[BKD][BM];      // 8 KB
  __shared__ float Bs[BKD][BN];      // 8 KB
  __shared__ float Dump[64 * BM];    // 32 KB, [local_col][row]

  const int tid = threadIdx.x;
  const int split = blockIdx.x;
  const int row0 = blockIdx.y * BM;
  const int col0 = split * KSPL;
  const int tr = tid & 15;           // row group
  const int tc = tid >> 4;           // col group
  const int sr = tid >> 1;           // staged row 0..127
  const int sq = (tid & 1) * 8;      // d-half 0/8
  const float xscale = xninv[row0 + sr];
  const float* xrow = x + (size_t)(row0 + sr) * DIMS + sq;
  const int scr = tid >> 1;          // scanned row 0..127
  const int sch = tid & 1;           // col-parity stream

  float tv0 = -INFINITY, tv1 = -INFINITY, tv2 = -INFINITY, tv3 = -INFINITY;
  int tk0 = 0, tk1 = 0, tk2 = 0, tk3 = 0;

  for (int kt = 0; kt < KSPL / BN; ++kt) {
    float acc[8][8];
    #pragma unroll
    for (int i = 0; i < 8; ++i)
      #pragma unroll
      for (int j = 0; j < 8; ++j) acc[i][j] = 0.f;

    const float* brow = wn + (size_t)(col0 + kt * BN + sr) * DIMS + sq;

    for (int dc = 0; dc < DIMS / BKD; ++dc) {
      __syncthreads();
      float4 a0 = *(const float4*)(xrow + dc * BKD);
      float4 a1 = *(const float4*)(xrow + dc * BKD + 4);
      float4 b0 = *(const float4*)(brow + dc * BKD);
      float4 b1 = *(const float4*)(brow + dc * BKD + 4);
      As[sq + 0][sr] = a0.x * xscale; As[sq + 1][sr] = a0.y * xscale;
      As[sq + 2][sr] = a0.z * xscale; As[sq + 3][sr] = a0.w * xscale;
      As[sq + 4][sr] = a1.x * xscale; As[sq + 5][sr] = a1.y * xscale;
      As[sq + 6][sr] = a1.z * xscale; As[sq + 7][sr] = a1.w * xscale;
      Bs[sq + 0][sr] = b0.x; Bs[sq + 1][sr] = b0.y;
      Bs[sq + 2][sr] = b0.z; Bs[sq + 3][sr] = b0.w;
      Bs[sq + 4][sr] = b1.x; Bs[sq + 5][sr] = b1.y;
      Bs[sq + 6][sr] = b1.z; Bs[sq + 7][sr] = b1.w;
      __syncthreads();
      #pragma unroll
      for (int d = 0; d < BKD; ++d) {
        float av[8], bv[8];
        float4 t;
        t = *(float4*)&As[d][tr * 4];      av[0]=t.x; av[1]=t.y; av[2]=t.z; av[3]=t.w;
        t = *(float4*)&As[d][64 + tr * 4]; av[4]=t.x; av[5]=t.y; av[6]=t.z; av[7]=t.w;
        t = *(float4*)&Bs[d][tc * 4];      bv[0]=t.x; bv[1]=t.y; bv[2]=t.z; bv[3]=t.w;
        t = *(float4*)&Bs[d][64 + tc * 4]; bv[4]=t.x; bv[5]=t.y; bv[6]=t.z; bv[7]=t.w;
        #pragma unroll
        for (int ri = 0; ri < 8; ++ri)
          #pragma unroll
          for (int cj = 0; cj < 8; ++cj)
            acc[ri][cj] += av[ri] * bv[cj];
      }
    }

    // dump + scan, 2 phases of 64 cols
    #pragma unroll
    for (int p = 0; p < 2; ++p) {
      __syncthreads();
      #pragma unroll
      for (int j = 0; j < 4; ++j) {
        int cl = tc * 4 + j;     // local col in this half
        int cj = p * 4 + j;      // acc col index
        *(float4*)&Dump[cl * BM + tr * 4] =
            float4{acc[0][cj], acc[1][cj], acc[2][cj], acc[3][cj]};
        *(float4*)&Dump[cl * BM + 64 + tr * 4] =
            float4{acc[4][cj], acc[5][cj], acc[6][cj], acc[7][cj]};
      }
      __syncthreads();
      int kbase = col0 + kt * BN + p * 64 + sch * 32;
      #pragma unroll
      for (int cc = 0; cc < 32; ++cc) {
        float cv = Dump[(sch * 32 + cc) * BM + scr];
        int ck = kbase + cc;
        CAS_INS(tv0, tk0);
        CAS_INS(tv1, tk1);
        CAS_INS(tv2, tk2);
        CAS_INS(tv3, tk3);
      }
    }
  }

  int slot = split * 2 + sch;
  size_t cb = (size_t)(row0 + scr) * 16 + slot * 4;
  candv[cb + 0] = tv0; candv[cb + 1] = tv1;
  candv[cb + 2] = tv2; candv[cb + 3] = tv3;
  candi[cb + 0] = tk0; candi[cb + 1] = tk1;
  candi[cb + 2] = tk2; candi[cb + 3] = tk3;
}

// ---------------------------------------------------------------------------
// refine: wave per row. Approx-top-8 of 16 candidates by fp32 GEMM value,
// then oracle-faithful fp32 distance:
//   xn  = fl(x / max(fl(sqrt(np_pairwise(x*x))), eps))   (per element)
//   dot = strictly d-ascending fp32 FMA chain over xn[d]*wn[k][d]  (sgemm)
//   d   = fl(fl(np_pairwise(xn*xn) + wn2[k]) - 2*dot)
// Rank by (d asc, k asc) (stable argsort ties -> lower index).
// Epilogue (quantized / ST / loss) in f64 (loose 2% thresholds).
// ---------------------------------------------------------------------------
#define WSTR 516   // LDS row stride for staged candidate rows:
                   // 16B-aligned (516*4 % 16 == 0) and conflict-free across
                   // the 8 chain lanes ((j*516) % 32 = j*4, all distinct).

__global__ __launch_bounds__(256) void refine_kernel(
    const float* __restrict__ x, const float* __restrict__ emb,
    const float* __restrict__ wn, const float* __restrict__ wnorm2,
    const float* __restrict__ candv, const int* __restrict__ candi,
    float* __restrict__ out, double* __restrict__ lossacc) {
  __shared__ float xbuf[4][512];          //  8 KB
  __shared__ float wbuf8[4][8 * WSTR];    // 64.5 KB
  int w = threadIdx.x >> 6, l = threadIdx.x & 63;
  int row = blockIdx.x * 4 + w;

  // ---- numpy-faithful xn + xn2 ----
  const float* xr = x + (size_t)row * DIMS + l * 8;
  float4 x0 = *(const float4*)xr;
  float4 x1 = *(const float4*)(xr + 4);
  *(float4*)&xbuf[w][l * 8]     = x0;
  *(float4*)&xbuf[w][l * 8 + 4] = x1;
  __syncthreads();
  float Sx = np_pairwise_sumsq_512(xbuf[w], l);
  float denx = fmaxf(__fsqrt_rn(Sx), 1e-12f);
  float xn[8];
  xn[0] = __fdiv_rn(x0.x, denx); xn[1] = __fdiv_rn(x0.y, denx);
  xn[2] = __fdiv_rn(x0.z, denx); xn[3] = __fdiv_rn(x0.w, denx);
  xn[4] = __fdiv_rn(x1.x, denx); xn[5] = __fdiv_rn(x1.y, denx);
  xn[6] = __fdiv_rn(x1.z, denx); xn[7] = __fdiv_rn(x1.w, denx);
  __syncthreads();   // pairwise chains done reading raw x
  *(float4*)&xbuf[w][l * 8]     = float4{xn[0], xn[1], xn[2], xn[3]};
  *(float4*)&xbuf[w][l * 8 + 4] = float4{xn[4], xn[5], xn[6], xn[7]};
  __syncthreads();
  float xn2 = np_pairwise_sumsq_512(xbuf[w], l);

  // ---- approx top-8 of 16 candidates (wave-argmax; no LDS) ----
  float cv = -INFINITY; int ck = 0x7fffffff;
  if (l < 16) { cv = candv[(size_t)row * 16 + l]; ck = candi[(size_t)row * 16 + l]; }
  int k8[8];
  #pragma unroll
  for (int it = 0; it < 8; ++it) {
    float mv = cv; int mk = ck;
    #pragma unroll
    for (int off = 1; off < 64; off <<= 1) {
      float ov = __shfl_xor(mv, off, 64);
      int ok = __shfl_xor(mk, off, 64);
      bool take = (ov > mv) || (ov == mv && ok < mk);
      mv = take ? ov : mv; mk = take ? ok : mk;
    }
    k8[it] = mk;
    if (ck == mk) cv = -INFINITY;   // remove winner from pool
  }

  // ---- stage the 8 candidate wn rows into LDS (coalesced) ----
  #pragma unroll
  for (int it = 0; it < 8; ++it) {
    const float* wr = wn + (size_t)k8[it] * DIMS + l * 8;
    float4 a = *(const float4*)wr;
    float4 b = *(const float4*)(wr + 4);
    *(float4*)&wbuf8[w][it * WSTR + l * 8]     = a;
    *(float4*)&wbuf8[w][it * WSTR + l * 8 + 4] = b;
  }
  __syncthreads();

  // ---- sgemm-faithful dot: strictly d-ascending fp32 FMA chain ----
  // lane j (mod 8) owns candidate j; xbuf read is same-address broadcast.
  {
    int j = l & 7;
    const float* xp = xbuf[w];
    const float* wp = &wbuf8[w][j * WSTR];
    float t = 0.f;
    #pragma unroll 8
    for (int d = 0; d < 512; ++d) t = fmaf(xp[d], wp[d], t);

    float d8[8];
    #pragma unroll
    for (int it = 0; it < 8; ++it) {
      float dot = __shfl(t, it, 64);             // lane it holds candidate it
      float s = __fadd_rn(xn2, wnorm2[k8[it]]);
      d8[it] = __fadd_rn(s, -(2.0f * dot));
    }

    // ---- top-3 by (d asc, k asc) ----
    float bd[3]; int bk[3];
    #pragma unroll
    for (int s = 0; s < 3; ++s) {
      float mv = INFINITY; int mk = 0x7fffffff;
      #pragma unroll
      for (int it = 0; it < 8; ++it) {
        bool take = (d8[it] < mv) || (d8[it] == mv && k8[it] < mk);
        mv = take ? d8[it] : mv; mk = take ? k8[it] : mk;
      }
      bd[s] = mv; bk[s] = mk;
      #pragma unroll
      for (int it = 0; it < 8; ++it)
        if (k8[it] == mk) d8[it] = INFINITY;
    }

    double i0 = 1.0 / (double)bd[0], i1 = 1.0 / (double)bd[1],
           i2 = 1.0 / (double)bd[2];
    double tot = (i0 + i1) + i2;
    double w0q = i0 / tot, w1q = i1 / tot, w2q = i2 / tot;

    if (l == 0) {
      float* oi = out + (size_t)N_ROWS * DIMS + 1 + (size_t)row * 3;
      oi[0] = (float)bk[0]; oi[1] = (float)bk[1]; oi[2] = (float)bk[2];
    }

    const float* e0 = emb + (size_t)bk[0] * DIMS + l * 8;
    const float* e1 = emb + (size_t)bk[1] * DIMS + l * 8;
    const float* e2 = emb + (size_t)bk[2] * DIMS + l * 8;
    float4 ea0 = *(const float4*)e0, eb0 = *(const float4*)(e0 + 4);
    float4 ea1 = *(const float4*)e1, eb1 = *(const float4*)(e1 + 4);
    float4 ea2 = *(const float4*)e2, eb2 = *(const float4*)(e2 + 4);
    double xs[8];
    xs[0] = x0.x; xs[1] = x0.y; xs[2] = x0.z; xs[3] = x0.w;
    xs[4] = x1.x; xs[5] = x1.y; xs[6] = x1.z; xs[7] = x1.w;
    double q[8];
    q[0] = w0q*(double)ea0.x + w1q*(double)ea1.x + w2q*(double)ea2.x;
    q[1] = w0q*(double)ea0.y + w1q*(double)ea1.y + w2q*(double)ea2.y;
    q[2] = w0q*(double)ea0.z + w1q*(double)ea1.z + w2q*(double)ea2.z;
    q[3] = w0q*(double)ea0.w + w1q*(double)ea1.w + w2q*(double)ea2.w;
    q[4] = w0q*(double)eb0.x + w1q*(double)eb1.x + w2q*(double)eb2.x;
    q[5] = w0q*(double)eb0.y + w1q*(double)eb1.y + w2q*(double)eb2.y;
    q[6] = w0q*(double)eb0.z + w1q*(double)eb1.z + w2q*(double)eb2.z;
    q[7] = w0q*(double)eb0.w + w1q*(double)eb1.w + w2q*(double)eb2.w;

    double lp = 0.0;
    float o[8];
    #pragma unroll
    for (int jj = 0; jj < 8; ++jj) {
      double diff = q[jj] - xs[jj];
      o[jj] = (float)(xs[jj] + diff);
      lp += diff * diff;
    }
    float* orow = out + (size_t)row * DIMS + l * 8;
    *(float4*)orow       = float4{o[0], o[1], o[2], o[3]};
    *(float4*)(orow + 4) = float4{o[4], o[5], o[6], o[7]};

    #pragma unroll
    for (int off = 1; off < 64; off <<= 1) lp += __shfl_xor(lp, off, 64);
    if (l == 0) atomicAdd(lossacc, lp);
  }
}

__global__ void loss_finalize_kernel(const double* __restrict__ lossacc,
                                     float* __restrict__ out) {
  double m = lossacc[0] / 16777216.0;   // N*D = 2^24, exact
  out[(size_t)N_ROWS * DIMS] = (float)(m + 0.25 * m);
}

// ---------------------------------------------------------------------------
extern "C" void kernel_launch(void* const* d_in, const int* in_sizes, int n_in,
                              void* d_out, int out_size, void* d_ws, size_t ws_size,
                              hipStream_t stream) {
  (void)in_sizes; (void)n_in; (void)out_size; (void)ws_size;
  const float* x   = (const float*)d_in[0];
  const float* emb = (const float*)d_in[1];
  float* out = (float*)d_out;
  char* ws = (char*)d_ws;

  float*  wn      = (float*)(ws);                 // K*D*4   = 16777216
  float*  wnorm2  = (float*)(ws + 16777216);      // K*4     = 32768
  float*  xninv   = (float*)(ws + 16809984);      // N*4     = 131072
  float*  candv   = (float*)(ws + 16941056);      // N*16*4  = 2097152
  int*    candi   = (int*)  (ws + 19038208);      // N*16*4  = 2097152
  double* lossacc = (double*)(ws + 21135360);     // 8

  prep_w_np_kernel<<<K_CODES / 4, 256, 0, stream>>>(emb, wn, wnorm2);
  prep_x_kernel<<<N_ROWS / 4, 256, 0, stream>>>(x, xninv);
  gemm_topk_kernel<<<dim3(SPLITS, N_ROWS / BM), 256, 0, stream>>>(
      x, wn, xninv, candv, candi);
  hipMemsetAsync(lossacc, 0, 8, stream);
  refine_kernel<<<N_ROWS / 4, 256, 0, stream>>>(
      x, emb, wn, wnorm2, candv, candi, out, lossacc);
  loss_finalize_kernel<<<1, 1, 0, stream>>>(lossacc, out);
}

// Round 5
// 1410.810 us; speedup vs baseline: 2.9916x; 2.9916x over previous
//
#include <hip/hip_runtime.h>
#include <cstdint>
#include <cstddef>

// Problem constants (fixed by reference)
#define N_ROWS  32768
#define DIMS    512
#define K_CODES 8192

// Old fp32 GEMM tiling (fallback path)
#define BM   128
#define BN   128
#define BKD  16
#define SPLITS 2
#define KSPL (K_CODES / SPLITS)   // 4096

typedef short    bf16x8 __attribute__((ext_vector_type(8)));
typedef float    f32x4  __attribute__((ext_vector_type(4)));

__device__ __forceinline__ unsigned short cvt_bf16_rne(float f) {
  union { float f; unsigned u; } c; c.f = f;
  unsigned r = c.u + 0x7FFFu + ((c.u >> 16) & 1u);
  return (unsigned short)(r >> 16);
}

// ===========================================================================
// Oracle model (validated round 4, absmax 4.8e-7):
//  - norms: numpy pairwise fp32; elementwise sqrt/max/div correctly rounded
//  - big dot: BLAS sgemm = one strictly d-ascending fp32 FMA chain
//  - d = fl(fl(xn2+wn2) - 2*dot); stable argsort ties -> lower index
// ===========================================================================

__device__ __forceinline__ float np_pairwise_sumsq_512(const float* buf, int l) {
  int blk = l >> 4, jv = (l >> 2) & 3, ln = l & 3;
  int cb = blk * 128 + jv * 4 + ln;
  float v = buf[cb];
  float r = __fmul_rn(v, v);
  #pragma unroll
  for (int i = 1; i < 8; ++i) {
    float t = buf[cb + 16 * i];
    r = __fadd_rn(r, __fmul_rn(t, t));
  }
  r = __fadd_rn(r, __shfl_xor(r, 4, 64));
  r = __fadd_rn(r, __shfl_xor(r, 8, 64));
  r = __fadd_rn(r, __shfl_xor(r, 1, 64));
  r = __fadd_rn(r, __shfl_xor(r, 2, 64));
  r = __fadd_rn(r, __shfl_xor(r, 16, 64));
  r = __fadd_rn(r, __shfl_xor(r, 32, 64));
  return r;
}

// ---------------------------------------------------------------------------
// prep_x: per-row inverse fp32 norm (approx path: candidates only)
// ---------------------------------------------------------------------------
__global__ __launch_bounds__(256) void prep_x_kernel(
    const float* __restrict__ x, float* __restrict__ xninv) {
  int row = blockIdx.x * 4 + (threadIdx.x >> 6);
  int l = threadIdx.x & 63;
  const float* xr = x + (size_t)row * DIMS + l * 8;
  float4 a = *(const float4*)xr;
  float4 b = *(const float4*)(xr + 4);
  float s = a.x*a.x + a.y*a.y + a.z*a.z + a.w*a.w
          + b.x*b.x + b.y*b.y + b.z*b.z + b.w*b.w;
  #pragma unroll
  for (int off = 1; off < 64; off <<= 1) s += __shfl_xor(s, off, 64);
  float den = fmaxf(sqrtf(s), 1e-12f);
  if (l == 0) xninv[row] = 1.0f / den;
}

// ---------------------------------------------------------------------------
// prep_w_np: numpy-faithful fp32 normalized codebook + wn2; optional bf16 copy
// ---------------------------------------------------------------------------
__global__ __launch_bounds__(256) void prep_w_np_kernel(
    const float* __restrict__ emb, float* __restrict__ wn,
    float* __restrict__ wnorm2, unsigned short* __restrict__ wnh) {
  __shared__ float buf[4][512];
  int w = threadIdx.x >> 6, l = threadIdx.x & 63;
  int row = blockIdx.x * 4 + w;
  const float* wr = emb + (size_t)row * DIMS + l * 8;
  float4 a = *(const float4*)wr;
  float4 b = *(const float4*)(wr + 4);
  *(float4*)&buf[w][l * 8]     = a;
  *(float4*)&buf[w][l * 8 + 4] = b;
  __syncthreads();
  float S = np_pairwise_sumsq_512(buf[w], l);
  float den = fmaxf(__fsqrt_rn(S), 1e-12f);
  float nv[8];
  nv[0] = __fdiv_rn(a.x, den); nv[1] = __fdiv_rn(a.y, den);
  nv[2] = __fdiv_rn(a.z, den); nv[3] = __fdiv_rn(a.w, den);
  nv[4] = __fdiv_rn(b.x, den); nv[5] = __fdiv_rn(b.y, den);
  nv[6] = __fdiv_rn(b.z, den); nv[7] = __fdiv_rn(b.w, den);
  __syncthreads();   // chains done reading raw w before overwrite
  *(float4*)&buf[w][l * 8]     = float4{nv[0], nv[1], nv[2], nv[3]};
  *(float4*)&buf[w][l * 8 + 4] = float4{nv[4], nv[5], nv[6], nv[7]};
  float* wo = wn + (size_t)row * DIMS + l * 8;
  *(float4*)wo       = float4{nv[0], nv[1], nv[2], nv[3]};
  *(float4*)(wo + 4) = float4{nv[4], nv[5], nv[6], nv[7]};
  if (wnh) {
    unsigned hv[4];
    #pragma unroll
    for (int j = 0; j < 4; ++j) {
      unsigned lo = cvt_bf16_rne(nv[2*j]);
      unsigned hi = cvt_bf16_rne(nv[2*j + 1]);
      hv[j] = lo | (hi << 16);
    }
    *(uint4*)(wnh + (size_t)row * DIMS + l * 8) =
        uint4{hv[0], hv[1], hv[2], hv[3]};
  }
  __syncthreads();
  float S2 = np_pairwise_sumsq_512(buf[w], l);
  if (l == 0) wnorm2[row] = S2;
}

// ===========================================================================
// MFMA candidate path: 16x16x32 bf16 (verified layouts:
//   A[m=lane&15][k=(lane>>4)*8+j], B[n=lane&15][k=(lane>>4)*8+j],
//   C: col=lane&15, row=(lane>>4)*4+reg)
// Block = 256 thr = 4 waves x 32 rows; A bf16 resident in VGPRs (128/lane).
// Per split (4096 cols): 64 col-tiles of 64; B staged in 4 k-chunks of 128.
// Candidates: packed u32 key = (value 20b | col-in-split 12b);
// per-lane top-2-of-4-cols prefilter -> LDS dump (reuses B buffer) ->
// per-row streaming top-8 (min/max bubble insert).
// ===========================================================================
#define MT_ROWS 128
#define MT_TILES 64
#define BSTR_B 272          // B LDS row stride in BYTES (128 bf16 + 8 pad)

__global__ __launch_bounds__(256, 2) void mfma_topk_kernel(
    const float* __restrict__ x, const unsigned short* __restrict__ wnh,
    const float* __restrict__ xninv, unsigned* __restrict__ candk) {
  __shared__ unsigned short Bs[64 * (BSTR_B / 2)];   // 17408 B
  unsigned* dump = (unsigned*)Bs;                    // 32 x 128 u32 = 16 KB

  const int tid = threadIdx.x;
  const int lane = tid & 63;
  const int wv = tid >> 6;
  const int row0 = blockIdx.x * MT_ROWS;
  const int split = blockIdx.y;
  const int col0 = split * 4096;
  const int l15 = lane & 15;
  const int lq = lane >> 4;

  // ---- A fragments: xn bf16, resident across all col-tiles ----
  bf16x8 afrag[2][16];
  #pragma unroll
  for (int rs = 0; rs < 2; ++rs) {
    int row = row0 + wv * 32 + rs * 16 + l15;
    float sc = xninv[row];
    const float* xp = x + (size_t)row * DIMS + lq * 8;
    #pragma unroll
    for (int ks = 0; ks < 16; ++ks) {
      float4 a = *(const float4*)(xp + ks * 32);
      float4 b = *(const float4*)(xp + ks * 32 + 4);
      bf16x8 f;
      f[0] = (short)cvt_bf16_rne(a.x * sc); f[1] = (short)cvt_bf16_rne(a.y * sc);
      f[2] = (short)cvt_bf16_rne(a.z * sc); f[3] = (short)cvt_bf16_rne(a.w * sc);
      f[4] = (short)cvt_bf16_rne(b.x * sc); f[5] = (short)cvt_bf16_rne(b.y * sc);
      f[6] = (short)cvt_bf16_rne(b.z * sc); f[7] = (short)cvt_bf16_rne(b.w * sc);
      afrag[rs][ks] = f;
    }
  }

  unsigned m[8];
  #pragma unroll
  for (int j = 0; j < 8; ++j) m[j] = 0u;

  const int scol = tid >> 2;        // staging col 0..63
  const int spart = tid & 3;        // staging k-part

  for (int t = 0; t < MT_TILES; ++t) {
    f32x4 acc[2][4];
    #pragma unroll
    for (int rs = 0; rs < 2; ++rs)
      #pragma unroll
      for (int cs = 0; cs < 4; ++cs)
        acc[rs][cs] = f32x4{0.f, 0.f, 0.f, 0.f};

    #pragma unroll 1
    for (int c = 0; c < 4; ++c) {
      // stage B chunk: cols [t*64,+64), k [c*128,+128)
      const char* src = (const char*)(wnh + (size_t)(col0 + t * 64 + scol) * DIMS
                                      + c * 128 + spart * 32);
      char* dst = (char*)Bs + scol * BSTR_B + spart * 64;
      uint4 s0 = *(const uint4*)(src);
      uint4 s1 = *(const uint4*)(src + 16);
      uint4 s2 = *(const uint4*)(src + 32);
      uint4 s3 = *(const uint4*)(src + 48);
      __syncthreads();              // prior chunk fully consumed
      *(uint4*)(dst)      = s0;
      *(uint4*)(dst + 16) = s1;
      *(uint4*)(dst + 32) = s2;
      *(uint4*)(dst + 48) = s3;
      __syncthreads();
      #pragma unroll
      for (int kk = 0; kk < 4; ++kk) {
        int ks = c * 4 + kk;
        bf16x8 bfr[4];
        #pragma unroll
        for (int cs = 0; cs < 4; ++cs)
          bfr[cs] = *(const bf16x8*)((const char*)Bs
                      + (cs * 16 + l15) * BSTR_B + kk * 64 + lq * 16);
        #pragma unroll
        for (int rs = 0; rs < 2; ++rs)
          #pragma unroll
          for (int cs = 0; cs < 4; ++cs)
            acc[rs][cs] = __builtin_amdgcn_mfma_f32_16x16x32_bf16(
                afrag[rs][ks], bfr[cs], acc[rs][cs], 0, 0, 0);
      }
    }
    __syncthreads();                // mfma B reads done; Bs reusable as dump

    // mini-reduce: per (row, col-residue-class) top-2-of-4 packed keys
    #pragma unroll
    for (int rs = 0; rs < 2; ++rs)
      #pragma unroll
      for (int rg = 0; rg < 4; ++rg) {
        unsigned kkey[4];
        #pragma unroll
        for (int cs = 0; cs < 4; ++cs) {
          float v = acc[rs][cs][rg];
          union { float f; unsigned u; } cu;
          cu.f = fmaf(v, 0.5f, 2.5f);
          kkey[cs] = ((cu.u << 9) & 0xFFFFF000u)
                   | (unsigned)(t * 64 + cs * 16 + l15);
        }
        unsigned h1 = max(kkey[0], kkey[1]), lo1 = min(kkey[0], kkey[1]);
        unsigned h2 = max(kkey[2], kkey[3]), lo2 = min(kkey[2], kkey[3]);
        unsigned m1 = max(h1, h2);
        unsigned m2 = max(min(h1, h2), max(lo1, lo2));
        int rowl = wv * 32 + rs * 16 + lq * 4 + rg;
        dump[(l15 * 2 + 0) * 128 + rowl] = m1;
        dump[(l15 * 2 + 1) * 128 + rowl] = m2;
      }
    __syncthreads();

    // per-row streaming top-8 (threads 0..127 own one row each)
    if (tid < 128) {
      #pragma unroll
      for (int q = 0; q < 32; ++q) {
        unsigned cv = dump[q * 128 + tid];
        #pragma unroll
        for (int j = 0; j < 8; ++j) {
          unsigned hi = max(m[j], cv), lo = min(m[j], cv);
          m[j] = hi; cv = lo;
        }
      }
    }
    __syncthreads();                // dump area free for next tile's staging
  }

  if (tid < 128) {
    unsigned* o = candk + (size_t)(row0 + tid) * 16 + split * 8;
    #pragma unroll
    for (int j = 0; j < 8; ++j) o[j] = m[j];
  }
}

// ---------------------------------------------------------------------------
// refine (MFMA path): decode 16 packed keys, approx-top-8, exact sgemm-chain
// rerank, top-3, weights/quantize/ST/loss. (Oracle-faithful scoring kept.)
// ---------------------------------------------------------------------------
#define WSTR 516

__global__ __launch_bounds__(256) void refine_mfma_kernel(
    const float* __restrict__ x, const float* __restrict__ emb,
    const float* __restrict__ wn, const float* __restrict__ wnorm2,
    const unsigned* __restrict__ candk,
    float* __restrict__ out, double* __restrict__ lossacc) {
  __shared__ float xbuf[4][512];
  __shared__ float wbuf8[4][8 * WSTR];
  int w = threadIdx.x >> 6, l = threadIdx.x & 63;
  int row = blockIdx.x * 4 + w;

  const float* xr = x + (size_t)row * DIMS + l * 8;
  float4 x0 = *(const float4*)xr;
  float4 x1 = *(const float4*)(xr + 4);
  *(float4*)&xbuf[w][l * 8]     = x0;
  *(float4*)&xbuf[w][l * 8 + 4] = x1;
  __syncthreads();
  float Sx = np_pairwise_sumsq_512(xbuf[w], l);
  float denx = fmaxf(__fsqrt_rn(Sx), 1e-12f);
  float xn[8];
  xn[0] = __fdiv_rn(x0.x, denx); xn[1] = __fdiv_rn(x0.y, denx);
  xn[2] = __fdiv_rn(x0.z, denx); xn[3] = __fdiv_rn(x0.w, denx);
  xn[4] = __fdiv_rn(x1.x, denx); xn[5] = __fdiv_rn(x1.y, denx);
  xn[6] = __fdiv_rn(x1.z, denx); xn[7] = __fdiv_rn(x1.w, denx);
  __syncthreads();
  *(float4*)&xbuf[w][l * 8]     = float4{xn[0], xn[1], xn[2], xn[3]};
  *(float4*)&xbuf[w][l * 8 + 4] = float4{xn[4], xn[5], xn[6], xn[7]};
  __syncthreads();
  float xn2 = np_pairwise_sumsq_512(xbuf[w], l);

  // decode candidates
  unsigned val = 0u; int col = 0x7fffffff;
  if (l < 16) {
    unsigned key = candk[(size_t)row * 16 + l];
    val = key >> 12;
    col = (l >> 3) * 4096 + (int)(key & 0xFFFu);
  }

  int k8[8];
  #pragma unroll
  for (int it = 0; it < 8; ++it) {
    unsigned mv = val; int mk = col;
    #pragma unroll
    for (int off = 1; off < 64; off <<= 1) {
      unsigned ov = (unsigned)__shfl_xor((int)mv, off, 64);
      int ok = __shfl_xor(mk, off, 64);
      bool take = (ov > mv) || (ov == mv && ok < mk);
      mv = take ? ov : mv; mk = take ? ok : mk;
    }
    k8[it] = mk;
    if (col == mk) val = 0u;
  }

  #pragma unroll
  for (int it = 0; it < 8; ++it) {
    const float* wr = wn + (size_t)k8[it] * DIMS + l * 8;
    float4 a = *(const float4*)wr;
    float4 b = *(const float4*)(wr + 4);
    *(float4*)&wbuf8[w][it * WSTR + l * 8]     = a;
    *(float4*)&wbuf8[w][it * WSTR + l * 8 + 4] = b;
  }
  __syncthreads();

  {
    int j = l & 7;
    const float* xp = xbuf[w];
    const float* wp = &wbuf8[w][j * WSTR];
    float t = 0.f;
    #pragma unroll 8
    for (int d = 0; d < 512; ++d) t = fmaf(xp[d], wp[d], t);

    float d8[8];
    #pragma unroll
    for (int it = 0; it < 8; ++it) {
      float dot = __shfl(t, it, 64);
      float s = __fadd_rn(xn2, wnorm2[k8[it]]);
      d8[it] = __fadd_rn(s, -(2.0f * dot));
    }

    float bd[3]; int bk[3];
    #pragma unroll
    for (int s = 0; s < 3; ++s) {
      float mv = INFINITY; int mk = 0x7fffffff;
      #pragma unroll
      for (int it = 0; it < 8; ++it) {
        bool take = (d8[it] < mv) || (d8[it] == mv && k8[it] < mk);
        mv = take ? d8[it] : mv; mk = take ? k8[it] : mk;
      }
      bd[s] = mv; bk[s] = mk;
      #pragma unroll
      for (int it = 0; it < 8; ++it)
        if (k8[it] == mk) d8[it] = INFINITY;
    }

    double i0 = 1.0 / (double)bd[0], i1 = 1.0 / (double)bd[1],
           i2 = 1.0 / (double)bd[2];
    double tot = (i0 + i1) + i2;
    double w0q = i0 / tot, w1q = i1 / tot, w2q = i2 / tot;

    if (l == 0) {
      float* oi = out + (size_t)N_ROWS * DIMS + 1 + (size_t)row * 3;
      oi[0] = (float)bk[0]; oi[1] = (float)bk[1]; oi[2] = (float)bk[2];
    }

    const float* e0 = emb + (size_t)bk[0] * DIMS + l * 8;
    const float* e1 = emb + (size_t)bk[1] * DIMS + l * 8;
    const float* e2 = emb + (size_t)bk[2] * DIMS + l * 8;
    float4 ea0 = *(const float4*)e0, eb0 = *(const float4*)(e0 + 4);
    float4 ea1 = *(const float4*)e1, eb1 = *(const float4*)(e1 + 4);
    float4 ea2 = *(const float4*)e2, eb2 = *(const float4*)(e2 + 4);
    double xs[8];
    xs[0] = x0.x; xs[1] = x0.y; xs[2] = x0.z; xs[3] = x0.w;
    xs[4] = x1.x; xs[5] = x1.y; xs[6] = x1.z; xs[7] = x1.w;
    double q[8];
    q[0] = w0q*(double)ea0.x + w1q*(double)ea1.x + w2q*(double)ea2.x;
    q[1] = w0q*(double)ea0.y + w1q*(double)ea1.y + w2q*(double)ea2.y;
    q[2] = w0q*(double)ea0.z + w1q*(double)ea1.z + w2q*(double)ea2.z;
    q[3] = w0q*(double)ea0.w + w1q*(double)ea1.w + w2q*(double)ea2.w;
    q[4] = w0q*(double)eb0.x + w1q*(double)eb1.x + w2q*(double)eb2.x;
    q[5] = w0q*(double)eb0.y + w1q*(double)eb1.y + w2q*(double)eb2.y;
    q[6] = w0q*(double)eb0.z + w1q*(double)eb1.z + w2q*(double)eb2.z;
    q[7] = w0q*(double)eb0.w + w1q*(double)eb1.w + w2q*(double)eb2.w;

    double lp = 0.0;
    float o[8];
    #pragma unroll
    for (int jj = 0; jj < 8; ++jj) {
      double diff = q[jj] - xs[jj];
      o[jj] = (float)(xs[jj] + diff);
      lp += diff * diff;
    }
    float* orow = out + (size_t)row * DIMS + l * 8;
    *(float4*)orow       = float4{o[0], o[1], o[2], o[3]};
    *(float4*)(orow + 4) = float4{o[4], o[5], o[6], o[7]};

    #pragma unroll
    for (int off = 1; off < 64; off <<= 1) lp += __shfl_xor(lp, off, 64);
    if (l == 0) atomicAdd(lossacc, lp);
  }
}

// ===========================================================================
// FALLBACK fp32 path (round-4, known-passing) — used if ws_size too small
// ===========================================================================
#define CAS_INS(TV, TK)                                         \
  { bool sw_ = cv > (TV); float v_ = (TV); int k_ = (TK);       \
    (TV) = sw_ ? cv : (TV); (TK) = sw_ ? ck : (TK);             \
    cv = sw_ ? v_ : cv;     ck = sw_ ? k_ : ck; }

__global__ __launch_bounds__(256) void gemm_topk_kernel(
    const float* __restrict__ x, const float* __restrict__ wn,
    const float* __restrict__ xninv,
    float* __restrict__ candv, int* __restrict__ candi) {
  __shared__ float As[BKD][BM];
  __shared__ float Bsh[BKD][BN];
  __shared__ float Dump[64 * BM];

  const int tid = threadIdx.x;
  const int split = blockIdx.x;
  const int row0 = blockIdx.y * BM;
  const int col0 = split * KSPL;
  const int tr = tid & 15;
  const int tc = tid >> 4;
  const int sr = tid >> 1;
  const int sq = (tid & 1) * 8;
  const float xscale = xninv[row0 + sr];
  const float* xrow = x + (size_t)(row0 + sr) * DIMS + sq;
  const int scr = tid >> 1;
  const int sch = tid & 1;

  float tv0 = -INFINITY, tv1 = -INFINITY, tv2 = -INFINITY, tv3 = -INFINITY;
  int tk0 = 0, tk1 = 0, tk2 = 0, tk3 = 0;

  for (int kt = 0; kt < KSPL / BN; ++kt) {
    float acc[8][8];
    #pragma unroll
    for (int i = 0; i < 8; ++i)
      #pragma unroll
      for (int j = 0; j < 8; ++j) acc[i][j] = 0.f;

    const float* brow = wn + (size_t)(col0 + kt * BN + sr) * DIMS + sq;

    for (int dc = 0; dc < DIMS / BKD; ++dc) {
      __syncthreads();
      float4 a0 = *(const float4*)(xrow + dc * BKD);
      float4 a1 = *(const float4*)(xrow + dc * BKD + 4);
      float4 b0 = *(const float4*)(brow + dc * BKD);
      float4 b1 = *(const float4*)(brow + dc * BKD + 4);
      As[sq + 0][sr] = a0.x * xscale; As[sq + 1][sr] = a0.y * xscale;
      As[sq + 2][sr] = a0.z * xscale; As[sq + 3][sr] = a0.w * xscale;
      As[sq + 4][sr] = a1.x * xscale; As[sq + 5][sr] = a1.y * xscale;
      As[sq + 6][sr] = a1.z * xscale; As[sq + 7][sr] = a1.w * xscale;
      Bsh[sq + 0][sr] = b0.x; Bsh[sq + 1][sr] = b0.y;
      Bsh[sq + 2][sr] = b0.z; Bsh[sq + 3][sr] = b0.w;
      Bsh[sq + 4][sr] = b1.x; Bsh[sq + 5][sr] = b1.y;
      Bsh[sq + 6][sr] = b1.z; Bsh[sq + 7][sr] = b1.w;
      __syncthreads();
      #pragma unroll
      for (int d = 0; d < BKD; ++d) {
        float av[8], bv[8];
        float4 t;
        t = *(float4*)&As[d][tr * 4];       av[0]=t.x; av[1]=t.y; av[2]=t.z; av[3]=t.w;
        t = *(float4*)&As[d][64 + tr * 4];  av[4]=t.x; av[5]=t.y; av[6]=t.z; av[7]=t.w;
        t = *(float4*)&Bsh[d][tc * 4];      bv[0]=t.x; bv[1]=t.y; bv[2]=t.z; bv[3]=t.w;
        t = *(float4*)&Bsh[d][64 + tc * 4]; bv[4]=t.x; bv[5]=t.y; bv[6]=t.z; bv[7]=t.w;
        #pragma unroll
        for (int ri = 0; ri < 8; ++ri)
          #pragma unroll
          for (int cj = 0; cj < 8; ++cj)
            acc[ri][cj] += av[ri] * bv[cj];
      }
    }

    #pragma unroll
    for (int p = 0; p < 2; ++p) {
      __syncthreads();
      #pragma unroll
      for (int j = 0; j < 4; ++j) {
        int cl = tc * 4 + j;
        int cj = p * 4 + j;
        *(float4*)&Dump[cl * BM + tr * 4] =
            float4{acc[0][cj], acc[1][cj], acc[2][cj], acc[3][cj]};
        *(float4*)&Dump[cl * BM + 64 + tr * 4] =
            float4{acc[4][cj], acc[5][cj], acc[6][cj], acc[7][cj]};
      }
      __syncthreads();
      int kbase = col0 + kt * BN + p * 64 + sch * 32;
      #pragma unroll
      for (int cc = 0; cc < 32; ++cc) {
        float cv = Dump[(sch * 32 + cc) * BM + scr];
        int ck = kbase + cc;
        CAS_INS(tv0, tk0);
        CAS_INS(tv1, tk1);
        CAS_INS(tv2, tk2);
        CAS_INS(tv3, tk3);
      }
    }
  }

  int slot = split * 2 + sch;
  size_t cb = (size_t)(row0 + scr) * 16 + slot * 4;
  candv[cb + 0] = tv0; candv[cb + 1] = tv1;
  candv[cb + 2] = tv2; candv[cb + 3] = tv3;
  candi[cb + 0] = tk0; candi[cb + 1] = tk1;
  candi[cb + 2] = tk2; candi[cb + 3] = tk3;
}

__global__ __launch_bounds__(256) void refine_kernel(
    const float* __restrict__ x, const float* __restrict__ emb,
    const float* __restrict__ wn, const float* __restrict__ wnorm2,
    const float* __restrict__ candv, const int* __restrict__ candi,
    float* __restrict__ out, double* __restrict__ lossacc) {
  __shared__ float xbuf[4][512];
  __shared__ float wbuf8[4][8 * WSTR];
  int w = threadIdx.x >> 6, l = threadIdx.x & 63;
  int row = blockIdx.x * 4 + w;

  const float* xr = x + (size_t)row * DIMS + l * 8;
  float4 x0 = *(const float4*)xr;
  float4 x1 = *(const float4*)(xr + 4);
  *(float4*)&xbuf[w][l * 8]     = x0;
  *(float4*)&xbuf[w][l * 8 + 4] = x1;
  __syncthreads();
  float Sx = np_pairwise_sumsq_512(xbuf[w], l);
  float denx = fmaxf(__fsqrt_rn(Sx), 1e-12f);
  float xn[8];
  xn[0] = __fdiv_rn(x0.x, denx); xn[1] = __fdiv_rn(x0.y, denx);
  xn[2] = __fdiv_rn(x0.z, denx); xn[3] = __fdiv_rn(x0.w, denx);
  xn[4] = __fdiv_rn(x1.x, denx); xn[5] = __fdiv_rn(x1.y, denx);
  xn[6] = __fdiv_rn(x1.z, denx); xn[7] = __fdiv_rn(x1.w, denx);
  __syncthreads();
  *(float4*)&xbuf[w][l * 8]     = float4{xn[0], xn[1], xn[2], xn[3]};
  *(float4*)&xbuf[w][l * 8 + 4] = float4{xn[4], xn[5], xn[6], xn[7]};
  __syncthreads();
  float xn2 = np_pairwise_sumsq_512(xbuf[w], l);

  float cv = -INFINITY; int ck = 0x7fffffff;
  if (l < 16) { cv = candv[(size_t)row * 16 + l]; ck = candi[(size_t)row * 16 + l]; }
  int k8[8];
  #pragma unroll
  for (int it = 0; it < 8; ++it) {
    float mv = cv; int mk = ck;
    #pragma unroll
    for (int off = 1; off < 64; off <<= 1) {
      float ov = __shfl_xor(mv, off, 64);
      int ok = __shfl_xor(mk, off, 64);
      bool take = (ov > mv) || (ov == mv && ok < mk);
      mv = take ? ov : mv; mk = take ? ok : mk;
    }
    k8[it] = mk;
    if (ck == mk) cv = -INFINITY;
  }

  #pragma unroll
  for (int it = 0; it < 8; ++it) {
    const float* wr = wn + (size_t)k8[it] * DIMS + l * 8;
    float4 a = *(const float4*)wr;
    float4 b = *(const float4*)(wr + 4);
    *(float4*)&wbuf8[w][it * WSTR + l * 8]     = a;
    *(float4*)&wbuf8[w][it * WSTR + l * 8 + 4] = b;
  }
  __syncthreads();

  {
    int j = l & 7;
    const float* xp = xbuf[w];
    const float* wp = &wbuf8[w][j * WSTR];
    float t = 0.f;
    #pragma unroll 8
    for (int d = 0; d < 512; ++d) t = fmaf(xp[d], wp[d], t);

    float d8[8];
    #pragma unroll
    for (int it = 0; it < 8; ++it) {
      float dot = __shfl(t, it, 64);
      float s = __fadd_rn(xn2, wnorm2[k8[it]]);
      d8[it] = __fadd_rn(s, -(2.0f * dot));
    }

    float bd[3]; int bk[3];
    #pragma unroll
    for (int s = 0; s < 3; ++s) {
      float mv = INFINITY; int mk = 0x7fffffff;
      #pragma unroll
      for (int it = 0; it < 8; ++it) {
        bool take = (d8[it] < mv) || (d8[it] == mv && k8[it] < mk);
        mv = take ? d8[it] : mv; mk = take ? k8[it] : mk;
      }
      bd[s] = mv; bk[s] = mk;
      #pragma unroll
      for (int it = 0; it < 8; ++it)
        if (k8[it] == mk) d8[it] = INFINITY;
    }

    double i0 = 1.0 / (double)bd[0], i1 = 1.0 / (double)bd[1],
           i2 = 1.0 / (double)bd[2];
    double tot = (i0 + i1) + i2;
    double w0q = i0 / tot, w1q = i1 / tot, w2q = i2 / tot;

    if (l == 0) {
      float* oi = out + (size_t)N_ROWS * DIMS + 1 + (size_t)row * 3;
      oi[0] = (float)bk[0]; oi[1] = (float)bk[1]; oi[2] = (float)bk[2];
    }

    const float* e0 = emb + (size_t)bk[0] * DIMS + l * 8;
    const float* e1 = emb + (size_t)bk[1] * DIMS + l * 8;
    const float* e2 = emb + (size_t)bk[2] * DIMS + l * 8;
    float4 ea0 = *(const float4*)e0, eb0 = *(const float4*)(e0 + 4);
    float4 ea1 = *(const float4*)e1, eb1 = *(const float4*)(e1 + 4);
    float4 ea2 = *(const float4*)e2, eb2 = *(const float4*)(e2 + 4);
    double xs[8];
    xs[0] = x0.x; xs[1] = x0.y; xs[2] = x0.z; xs[3] = x0.w;
    xs[4] = x1.x; xs[5] = x1.y; xs[6] = x1.z; xs[7] = x1.w;
    double q[8];
    q[0] = w0q*(double)ea0.x + w1q*(double)ea1.x + w2q*(double)ea2.x;
    q[1] = w0q*(double)ea0.y + w1q*(double)ea1.y + w2q*(double)ea2.y;
    q[2] = w0q*(double)ea0.z + w1q*(double)ea1.z + w2q*(double)ea2.z;
    q[3] = w0q*(double)ea0.w + w1q*(double)ea1.w + w2q*(double)ea2.w;
    q[4] = w0q*(double)eb0.x + w1q*(double)eb1.x + w2q*(double)eb2.x;
    q[5] = w0q*(double)eb0.y + w1q*(double)eb1.y + w2q*(double)eb2.y;
    q[6] = w0q*(double)eb0.z + w1q*(double)eb1.z + w2q*(double)eb2.z;
    q[7] = w0q*(double)eb0.w + w1q*(double)eb1.w + w2q*(double)eb2.w;

    double lp = 0.0;
    float o[8];
    #pragma unroll
    for (int jj = 0; jj < 8; ++jj) {
      double diff = q[jj] - xs[jj];
      o[jj] = (float)(xs[jj] + diff);
      lp += diff * diff;
    }
    float* orow = out + (size_t)row * DIMS + l * 8;
    *(float4*)orow       = float4{o[0], o[1], o[2], o[3]};
    *(float4*)(orow + 4) = float4{o[4], o[5], o[6], o[7]};

    #pragma unroll
    for (int off = 1; off < 64; off <<= 1) lp += __shfl_xor(lp, off, 64);
    if (l == 0) atomicAdd(lossacc, lp);
  }
}

__global__ void loss_finalize_kernel(const double* __restrict__ lossacc,
                                     float* __restrict__ out) {
  double m = lossacc[0] / 16777216.0;   // N*D = 2^24, exact
  out[(size_t)N_ROWS * DIMS] = (float)(m + 0.25 * m);
}

// ---------------------------------------------------------------------------
extern "C" void kernel_launch(void* const* d_in, const int* in_sizes, int n_in,
                              void* d_out, int out_size, void* d_ws, size_t ws_size,
                              hipStream_t stream) {
  (void)in_sizes; (void)n_in; (void)out_size;
  const float* x   = (const float*)d_in[0];
  const float* emb = (const float*)d_in[1];
  float* out = (float*)d_out;
  char* ws = (char*)d_ws;

  if (ws_size >= 27426824) {
    // ---- MFMA path ----
    float*          wn      = (float*)(ws);                  // 16777216
    float*          wnorm2  = (float*)(ws + 16777216);       // 32768
    float*          xninv   = (float*)(ws + 16809984);       // 131072
    unsigned short* wnh     = (unsigned short*)(ws + 16941056); // 8388608
    unsigned*       candk   = (unsigned*)(ws + 25329664);    // 2097152
    double*         lossacc = (double*)(ws + 27426816);      // 8

    prep_w_np_kernel<<<K_CODES / 4, 256, 0, stream>>>(emb, wn, wnorm2, wnh);
    prep_x_kernel<<<N_ROWS / 4, 256, 0, stream>>>(x, xninv);
    mfma_topk_kernel<<<dim3(N_ROWS / MT_ROWS, 2), 256, 0, stream>>>(
        x, wnh, xninv, candk);
    hipMemsetAsync(lossacc, 0, 8, stream);
    refine_mfma_kernel<<<N_ROWS / 4, 256, 0, stream>>>(
        x, emb, wn, wnorm2, candk, out, lossacc);
    loss_finalize_kernel<<<1, 1, 0, stream>>>(lossacc, out);
  } else {
    // ---- fallback fp32 path (round-4, known-passing) ----
    float*  wn      = (float*)(ws);
    float*  wnorm2  = (float*)(ws + 16777216);
    float*  xninv   = (float*)(ws + 16809984);
    float*  candv   = (float*)(ws + 16941056);
    int*    candi   = (int*)  (ws + 19038208);
    double* lossacc = (double*)(ws + 21135360);

    prep_w_np_kernel<<<K_CODES / 4, 256, 0, stream>>>(emb, wn, wnorm2, nullptr);
    prep_x_kernel<<<N_ROWS / 4, 256, 0, stream>>>(x, xninv);
    gemm_topk_kernel<<<dim3(SPLITS, N_ROWS / BM), 256, 0, stream>>>(
        x, wn, xninv, candv, candi);
    hipMemsetAsync(lossacc, 0, 8, stream);
    refine_kernel<<<N_ROWS / 4, 256, 0, stream>>>(
        x, emb, wn, wnorm2, candv, candi, out, lossacc);
    loss_finalize_kernel<<<1, 1, 0, stream>>>(lossacc, out);
  }
}

// Round 6
// 1298.643 us; speedup vs baseline: 3.2499x; 1.0864x over previous
//
#include <hip/hip_runtime.h>
#include <cstdint>
#include <cstddef>

// Problem constants (fixed by reference)
#define N_ROWS  32768
#define DIMS    512
#define K_CODES 8192

// Old fp32 GEMM tiling (fallback path)
#define BM   128
#define BN   128
#define BKD  16
#define SPLITS 2
#define KSPL (K_CODES / SPLITS)   // 4096

typedef short    bf16x8 __attribute__((ext_vector_type(8)));
typedef float    f32x4  __attribute__((ext_vector_type(4)));

__device__ __forceinline__ unsigned short cvt_bf16_rne(float f) {
  union { float f; unsigned u; } c; c.f = f;
  unsigned r = c.u + 0x7FFFu + ((c.u >> 16) & 1u);
  return (unsigned short)(r >> 16);
}

// ===========================================================================
// Oracle model (validated round 4, absmax 4.8e-7):
//  - norms: numpy pairwise fp32; elementwise sqrt/max/div correctly rounded
//  - big dot: BLAS sgemm = one strictly d-ascending fp32 FMA chain
//  - d = fl(fl(xn2+wn2) - 2*dot); stable argsort ties -> lower index
// ===========================================================================

__device__ __forceinline__ float np_pairwise_sumsq_512(const float* buf, int l) {
  int blk = l >> 4, jv = (l >> 2) & 3, ln = l & 3;
  int cb = blk * 128 + jv * 4 + ln;
  float v = buf[cb];
  float r = __fmul_rn(v, v);
  #pragma unroll
  for (int i = 1; i < 8; ++i) {
    float t = buf[cb + 16 * i];
    r = __fadd_rn(r, __fmul_rn(t, t));
  }
  r = __fadd_rn(r, __shfl_xor(r, 4, 64));
  r = __fadd_rn(r, __shfl_xor(r, 8, 64));
  r = __fadd_rn(r, __shfl_xor(r, 1, 64));
  r = __fadd_rn(r, __shfl_xor(r, 2, 64));
  r = __fadd_rn(r, __shfl_xor(r, 16, 64));
  r = __fadd_rn(r, __shfl_xor(r, 32, 64));
  return r;
}

// ---------------------------------------------------------------------------
// prep_x: per-row inverse fp32 norm (approx path: candidates only)
// ---------------------------------------------------------------------------
__global__ __launch_bounds__(256) void prep_x_kernel(
    const float* __restrict__ x, float* __restrict__ xninv) {
  int row = blockIdx.x * 4 + (threadIdx.x >> 6);
  int l = threadIdx.x & 63;
  const float* xr = x + (size_t)row * DIMS + l * 8;
  float4 a = *(const float4*)xr;
  float4 b = *(const float4*)(xr + 4);
  float s = a.x*a.x + a.y*a.y + a.z*a.z + a.w*a.w
          + b.x*b.x + b.y*b.y + b.z*b.z + b.w*b.w;
  #pragma unroll
  for (int off = 1; off < 64; off <<= 1) s += __shfl_xor(s, off, 64);
  float den = fmaxf(sqrtf(s), 1e-12f);
  if (l == 0) xninv[row] = 1.0f / den;
}

// ---------------------------------------------------------------------------
// prep_w_np: numpy-faithful fp32 normalized codebook + wn2; optional bf16 copy
// ---------------------------------------------------------------------------
__global__ __launch_bounds__(256) void prep_w_np_kernel(
    const float* __restrict__ emb, float* __restrict__ wn,
    float* __restrict__ wnorm2, unsigned short* __restrict__ wnh) {
  __shared__ float buf[4][512];
  int w = threadIdx.x >> 6, l = threadIdx.x & 63;
  int row = blockIdx.x * 4 + w;
  const float* wr = emb + (size_t)row * DIMS + l * 8;
  float4 a = *(const float4*)wr;
  float4 b = *(const float4*)(wr + 4);
  *(float4*)&buf[w][l * 8]     = a;
  *(float4*)&buf[w][l * 8 + 4] = b;
  __syncthreads();
  float S = np_pairwise_sumsq_512(buf[w], l);
  float den = fmaxf(__fsqrt_rn(S), 1e-12f);
  float nv[8];
  nv[0] = __fdiv_rn(a.x, den); nv[1] = __fdiv_rn(a.y, den);
  nv[2] = __fdiv_rn(a.z, den); nv[3] = __fdiv_rn(a.w, den);
  nv[4] = __fdiv_rn(b.x, den); nv[5] = __fdiv_rn(b.y, den);
  nv[6] = __fdiv_rn(b.z, den); nv[7] = __fdiv_rn(b.w, den);
  __syncthreads();   // chains done reading raw w before overwrite
  *(float4*)&buf[w][l * 8]     = float4{nv[0], nv[1], nv[2], nv[3]};
  *(float4*)&buf[w][l * 8 + 4] = float4{nv[4], nv[5], nv[6], nv[7]};
  float* wo = wn + (size_t)row * DIMS + l * 8;
  *(float4*)wo       = float4{nv[0], nv[1], nv[2], nv[3]};
  *(float4*)(wo + 4) = float4{nv[4], nv[5], nv[6], nv[7]};
  if (wnh) {
    unsigned hv[4];
    #pragma unroll
    for (int j = 0; j < 4; ++j) {
      unsigned lo = cvt_bf16_rne(nv[2*j]);
      unsigned hi = cvt_bf16_rne(nv[2*j + 1]);
      hv[j] = lo | (hi << 16);
    }
    *(uint4*)(wnh + (size_t)row * DIMS + l * 8) =
        uint4{hv[0], hv[1], hv[2], hv[3]};
  }
  __syncthreads();
  float S2 = np_pairwise_sumsq_512(buf[w], l);
  if (l == 0) wnorm2[row] = S2;
}

// ===========================================================================
// MFMA candidate path v2:
//  - XCD-pinned split: xcd = bid&7 -> split = xcd&1, so each XCD's 64
//    co-resident blocks stream ONE 4 MB B-split that fits its private L2.
//  - software-pipelined B staging (prefetch next chunk into regs pre-MFMA)
//  - scan across all 256 threads (2 thr/row x 16 queue entries) + end merge
// ===========================================================================
#define MT_ROWS 128
#define MT_TILES 64
#define BSTR_B 272          // B LDS row stride in BYTES (128 bf16 + 8 pad)
#define DSTR   33           // dump row stride in dwords

__global__ __launch_bounds__(256, 2) void mfma_topk_kernel(
    const float* __restrict__ x, const unsigned short* __restrict__ wnh,
    const float* __restrict__ xninv, unsigned* __restrict__ candk) {
  __shared__ unsigned short Bs[64 * (BSTR_B / 2)];   // 17408 B
  unsigned* dump = (unsigned*)Bs;                    // 128 x 33 u32 = 16.9 KB

  const int tid = threadIdx.x;
  const int lane = tid & 63;
  const int wv = tid >> 6;
  const int bid = blockIdx.x;
  const int xcd = bid & 7;
  const int split = xcd & 1;
  const int rowgrp = ((bid >> 3) << 2) | (xcd >> 1);
  const int row0 = rowgrp * MT_ROWS;
  const int col0 = split * 4096;
  const int l15 = lane & 15;
  const int lq = lane >> 4;

  // ---- A fragments: xn bf16, resident across all col-tiles ----
  bf16x8 afrag[2][16];
  #pragma unroll
  for (int rs = 0; rs < 2; ++rs) {
    int row = row0 + wv * 32 + rs * 16 + l15;
    float sc = xninv[row];
    const float* xp = x + (size_t)row * DIMS + lq * 8;
    #pragma unroll
    for (int ks = 0; ks < 16; ++ks) {
      float4 a = *(const float4*)(xp + ks * 32);
      float4 b = *(const float4*)(xp + ks * 32 + 4);
      bf16x8 f;
      f[0] = (short)cvt_bf16_rne(a.x * sc); f[1] = (short)cvt_bf16_rne(a.y * sc);
      f[2] = (short)cvt_bf16_rne(a.z * sc); f[3] = (short)cvt_bf16_rne(a.w * sc);
      f[4] = (short)cvt_bf16_rne(b.x * sc); f[5] = (short)cvt_bf16_rne(b.y * sc);
      f[6] = (short)cvt_bf16_rne(b.z * sc); f[7] = (short)cvt_bf16_rne(b.w * sc);
      afrag[rs][ks] = f;
    }
  }

  unsigned m[8];
  #pragma unroll
  for (int j = 0; j < 8; ++j) m[j] = 0u;

  const int scol = tid >> 2;        // staging col 0..63
  const int spart = tid & 3;        // staging k-part

  // prefetch (t=0, c=0)
  uint4 s0, s1, s2, s3;
  {
    const char* p = (const char*)wnh
        + ((size_t)(col0 + scol) * DIMS) * 2 + spart * 64;
    s0 = *(const uint4*)(p);
    s1 = *(const uint4*)(p + 16);
    s2 = *(const uint4*)(p + 32);
    s3 = *(const uint4*)(p + 48);
  }

  for (int t = 0; t < MT_TILES; ++t) {
    f32x4 acc[2][4];
    #pragma unroll
    for (int rs = 0; rs < 2; ++rs)
      #pragma unroll
      for (int cs = 0; cs < 4; ++cs)
        acc[rs][cs] = f32x4{0.f, 0.f, 0.f, 0.f};

    #pragma unroll 1
    for (int c = 0; c < 4; ++c) {
      __syncthreads();              // Bs consumers (prev MFMA / scan) done
      char* dst = (char*)Bs + scol * BSTR_B + spart * 64;
      *(uint4*)(dst)      = s0;
      *(uint4*)(dst + 16) = s1;
      *(uint4*)(dst + 32) = s2;
      *(uint4*)(dst + 48) = s3;
      // prefetch next chunk (overlaps MFMAs + barriers)
      int nt = t + ((c + 1) >> 2);
      int nc = (c + 1) & 3;
      if (nt < MT_TILES) {
        const char* p = (const char*)wnh
            + ((size_t)(col0 + nt * 64 + scol) * DIMS) * 2
            + nc * 256 + spart * 64;
        s0 = *(const uint4*)(p);
        s1 = *(const uint4*)(p + 16);
        s2 = *(const uint4*)(p + 32);
        s3 = *(const uint4*)(p + 48);
      }
      __syncthreads();
      #pragma unroll
      for (int kk = 0; kk < 4; ++kk) {
        int ks = c * 4 + kk;
        bf16x8 bfr[4];
        #pragma unroll
        for (int cs = 0; cs < 4; ++cs)
          bfr[cs] = *(const bf16x8*)((const char*)Bs
                      + (cs * 16 + l15) * BSTR_B + kk * 64 + lq * 16);
        #pragma unroll
        for (int rs = 0; rs < 2; ++rs)
          #pragma unroll
          for (int cs = 0; cs < 4; ++cs)
            acc[rs][cs] = __builtin_amdgcn_mfma_f32_16x16x32_bf16(
                afrag[rs][ks], bfr[cs], acc[rs][cs], 0, 0, 0);
      }
    }
    __syncthreads();                // mfma B reads done; Bs reusable as dump

    // mini-reduce: per (row, col-residue-class) top-2-of-4 packed keys
    #pragma unroll
    for (int rs = 0; rs < 2; ++rs)
      #pragma unroll
      for (int rg = 0; rg < 4; ++rg) {
        unsigned kkey[4];
        #pragma unroll
        for (int cs = 0; cs < 4; ++cs) {
          float v = acc[rs][cs][rg];
          union { float f; unsigned u; } cu;
          cu.f = fmaf(v, 0.5f, 2.5f);
          kkey[cs] = ((cu.u << 9) & 0xFFFFF000u)
                   | (unsigned)(t * 64 + cs * 16 + l15);
        }
        unsigned h1 = max(kkey[0], kkey[1]), lo1 = min(kkey[0], kkey[1]);
        unsigned h2 = max(kkey[2], kkey[3]), lo2 = min(kkey[2], kkey[3]);
        unsigned m1 = max(h1, h2);
        unsigned m2 = max(min(h1, h2), max(lo1, lo2));
        int rowl = wv * 32 + rs * 16 + lq * 4 + rg;
        dump[rowl * DSTR + l15 * 2 + 0] = m1;
        dump[rowl * DSTR + l15 * 2 + 1] = m2;
      }
    __syncthreads();

    // streaming top-8: 2 threads per row, 16 queue entries each
    {
      int srow = tid & 127;
      int qb = (tid >> 7) * 16;
      #pragma unroll
      for (int q = 0; q < 16; ++q) {
        unsigned cv = dump[srow * DSTR + qb + q];
        #pragma unroll
        for (int j = 0; j < 8; ++j) {
          unsigned hi = max(m[j], cv), lo = min(m[j], cv);
          m[j] = hi; cv = lo;
        }
      }
    }
    // loop-top barrier protects Bs against next tile's staging write
  }

  // merge the two partial top-8s per row, store
  __syncthreads();
  if (tid >= 128) {
    #pragma unroll
    for (int j = 0; j < 8; ++j) dump[(tid & 127) * DSTR + 16 + j] = m[j];
  }
  __syncthreads();
  if (tid < 128) {
    #pragma unroll
    for (int j = 0; j < 8; ++j) {
      unsigned cv = dump[tid * DSTR + 16 + j];
      #pragma unroll
      for (int jj = 0; jj < 8; ++jj) {
        unsigned hi = max(m[jj], cv), lo = min(m[jj], cv);
        m[jj] = hi; cv = lo;
      }
    }
    unsigned* o = candk + (size_t)(row0 + tid) * 16 + split * 8;
    #pragma unroll
    for (int j = 0; j < 8; ++j) o[j] = m[j];
  }
}

// ---------------------------------------------------------------------------
// refine (MFMA path): decode 16 packed keys, approx-top-8, exact sgemm-chain
// rerank, top-3, weights/quantize/ST/loss. (Oracle-faithful scoring kept.)
// ---------------------------------------------------------------------------
#define WSTR 516

__global__ __launch_bounds__(256) void refine_mfma_kernel(
    const float* __restrict__ x, const float* __restrict__ emb,
    const float* __restrict__ wn, const float* __restrict__ wnorm2,
    const unsigned* __restrict__ candk,
    float* __restrict__ out, double* __restrict__ lossacc) {
  __shared__ float xbuf[4][512];
  __shared__ float wbuf8[4][8 * WSTR];
  int w = threadIdx.x >> 6, l = threadIdx.x & 63;
  int row = blockIdx.x * 4 + w;

  const float* xr = x + (size_t)row * DIMS + l * 8;
  float4 x0 = *(const float4*)xr;
  float4 x1 = *(const float4*)(xr + 4);
  *(float4*)&xbuf[w][l * 8]     = x0;
  *(float4*)&xbuf[w][l * 8 + 4] = x1;
  __syncthreads();
  float Sx = np_pairwise_sumsq_512(xbuf[w], l);
  float denx = fmaxf(__fsqrt_rn(Sx), 1e-12f);
  float xn[8];
  xn[0] = __fdiv_rn(x0.x, denx); xn[1] = __fdiv_rn(x0.y, denx);
  xn[2] = __fdiv_rn(x0.z, denx); xn[3] = __fdiv_rn(x0.w, denx);
  xn[4] = __fdiv_rn(x1.x, denx); xn[5] = __fdiv_rn(x1.y, denx);
  xn[6] = __fdiv_rn(x1.z, denx); xn[7] = __fdiv_rn(x1.w, denx);
  __syncthreads();
  *(float4*)&xbuf[w][l * 8]     = float4{xn[0], xn[1], xn[2], xn[3]};
  *(float4*)&xbuf[w][l * 8 + 4] = float4{xn[4], xn[5], xn[6], xn[7]};
  __syncthreads();
  float xn2 = np_pairwise_sumsq_512(xbuf[w], l);

  // decode candidates
  unsigned val = 0u; int col = 0x7fffffff;
  if (l < 16) {
    unsigned key = candk[(size_t)row * 16 + l];
    val = key >> 12;
    col = (l >> 3) * 4096 + (int)(key & 0xFFFu);
  }

  int k8[8];
  #pragma unroll
  for (int it = 0; it < 8; ++it) {
    unsigned mv = val; int mk = col;
    #pragma unroll
    for (int off = 1; off < 64; off <<= 1) {
      unsigned ov = (unsigned)__shfl_xor((int)mv, off, 64);
      int ok = __shfl_xor(mk, off, 64);
      bool take = (ov > mv) || (ov == mv && ok < mk);
      mv = take ? ov : mv; mk = take ? ok : mk;
    }
    k8[it] = mk;
    if (col == mk) val = 0u;
  }

  #pragma unroll
  for (int it = 0; it < 8; ++it) {
    const float* wr = wn + (size_t)k8[it] * DIMS + l * 8;
    float4 a = *(const float4*)wr;
    float4 b = *(const float4*)(wr + 4);
    *(float4*)&wbuf8[w][it * WSTR + l * 8]     = a;
    *(float4*)&wbuf8[w][it * WSTR + l * 8 + 4] = b;
  }
  __syncthreads();

  {
    int j = l & 7;
    const float* xp = xbuf[w];
    const float* wp = &wbuf8[w][j * WSTR];
    float t = 0.f;
    #pragma unroll 8
    for (int d = 0; d < 512; ++d) t = fmaf(xp[d], wp[d], t);

    float d8[8];
    #pragma unroll
    for (int it = 0; it < 8; ++it) {
      float dot = __shfl(t, it, 64);
      float s = __fadd_rn(xn2, wnorm2[k8[it]]);
      d8[it] = __fadd_rn(s, -(2.0f * dot));
    }

    float bd[3]; int bk[3];
    #pragma unroll
    for (int s = 0; s < 3; ++s) {
      float mv = INFINITY; int mk = 0x7fffffff;
      #pragma unroll
      for (int it = 0; it < 8; ++it) {
        bool take = (d8[it] < mv) || (d8[it] == mv && k8[it] < mk);
        mv = take ? d8[it] : mv; mk = take ? k8[it] : mk;
      }
      bd[s] = mv; bk[s] = mk;
      #pragma unroll
      for (int it = 0; it < 8; ++it)
        if (k8[it] == mk) d8[it] = INFINITY;
    }

    double i0 = 1.0 / (double)bd[0], i1 = 1.0 / (double)bd[1],
           i2 = 1.0 / (double)bd[2];
    double tot = (i0 + i1) + i2;
    double w0q = i0 / tot, w1q = i1 / tot, w2q = i2 / tot;

    if (l == 0) {
      float* oi = out + (size_t)N_ROWS * DIMS + 1 + (size_t)row * 3;
      oi[0] = (float)bk[0]; oi[1] = (float)bk[1]; oi[2] = (float)bk[2];
    }

    const float* e0 = emb + (size_t)bk[0] * DIMS + l * 8;
    const float* e1 = emb + (size_t)bk[1] * DIMS + l * 8;
    const float* e2 = emb + (size_t)bk[2] * DIMS + l * 8;
    float4 ea0 = *(const float4*)e0, eb0 = *(const float4*)(e0 + 4);
    float4 ea1 = *(const float4*)e1, eb1 = *(const float4*)(e1 + 4);
    float4 ea2 = *(const float4*)e2, eb2 = *(const float4*)(e2 + 4);
    double xs[8];
    xs[0] = x0.x; xs[1] = x0.y; xs[2] = x0.z; xs[3] = x0.w;
    xs[4] = x1.x; xs[5] = x1.y; xs[6] = x1.z; xs[7] = x1.w;
    double q[8];
    q[0] = w0q*(double)ea0.x + w1q*(double)ea1.x + w2q*(double)ea2.x;
    q[1] = w0q*(double)ea0.y + w1q*(double)ea1.y + w2q*(double)ea2.y;
    q[2] = w0q*(double)ea0.z + w1q*(double)ea1.z + w2q*(double)ea2.z;
    q[3] = w0q*(double)ea0.w + w1q*(double)ea1.w + w2q*(double)ea2.w;
    q[4] = w0q*(double)eb0.x + w1q*(double)eb1.x + w2q*(double)eb2.x;
    q[5] = w0q*(double)eb0.y + w1q*(double)eb1.y + w2q*(double)eb2.y;
    q[6] = w0q*(double)eb0.z + w1q*(double)eb1.z + w2q*(double)eb2.z;
    q[7] = w0q*(double)eb0.w + w1q*(double)eb1.w + w2q*(double)eb2.w;

    double lp = 0.0;
    float o[8];
    #pragma unroll
    for (int jj = 0; jj < 8; ++jj) {
      double diff = q[jj] - xs[jj];
      o[jj] = (float)(xs[jj] + diff);
      lp += diff * diff;
    }
    float* orow = out + (size_t)row * DIMS + l * 8;
    *(float4*)orow       = float4{o[0], o[1], o[2], o[3]};
    *(float4*)(orow + 4) = float4{o[4], o[5], o[6], o[7]};

    #pragma unroll
    for (int off = 1; off < 64; off <<= 1) lp += __shfl_xor(lp, off, 64);
    if (l == 0) atomicAdd(lossacc, lp);
  }
}

// ===========================================================================
// FALLBACK fp32 path (round-4, known-passing) — used if ws_size too small
// ===========================================================================
#define CAS_INS(TV, TK)                                         \
  { bool sw_ = cv > (TV); float v_ = (TV); int k_ = (TK);       \
    (TV) = sw_ ? cv : (TV); (TK) = sw_ ? ck : (TK);             \
    cv = sw_ ? v_ : cv;     ck = sw_ ? k_ : ck; }

__global__ __launch_bounds__(256) void gemm_topk_kernel(
    const float* __restrict__ x, const float* __restrict__ wn,
    const float* __restrict__ xninv,
    float* __restrict__ candv, int* __restrict__ candi) {
  __shared__ float As[BKD][BM];
  __shared__ float Bsh[BKD][BN];
  __shared__ float Dump[64 * BM];

  const int tid = threadIdx.x;
  const int split = blockIdx.x;
  const int row0 = blockIdx.y * BM;
  const int col0 = split * KSPL;
  const int tr = tid & 15;
  const int tc = tid >> 4;
  const int sr = tid >> 1;
  const int sq = (tid & 1) * 8;
  const float xscale = xninv[row0 + sr];
  const float* xrow = x + (size_t)(row0 + sr) * DIMS + sq;
  const int scr = tid >> 1;
  const int sch = tid & 1;

  float tv0 = -INFINITY, tv1 = -INFINITY, tv2 = -INFINITY, tv3 = -INFINITY;
  int tk0 = 0, tk1 = 0, tk2 = 0, tk3 = 0;

  for (int kt = 0; kt < KSPL / BN; ++kt) {
    float acc[8][8];
    #pragma unroll
    for (int i = 0; i < 8; ++i)
      #pragma unroll
      for (int j = 0; j < 8; ++j) acc[i][j] = 0.f;

    const float* brow = wn + (size_t)(col0 + kt * BN + sr) * DIMS + sq;

    for (int dc = 0; dc < DIMS / BKD; ++dc) {
      __syncthreads();
      float4 a0 = *(const float4*)(xrow + dc * BKD);
      float4 a1 = *(const float4*)(xrow + dc * BKD + 4);
      float4 b0 = *(const float4*)(brow + dc * BKD);
      float4 b1 = *(const float4*)(brow + dc * BKD + 4);
      As[sq + 0][sr] = a0.x * xscale; As[sq + 1][sr] = a0.y * xscale;
      As[sq + 2][sr] = a0.z * xscale; As[sq + 3][sr] = a0.w * xscale;
      As[sq + 4][sr] = a1.x * xscale; As[sq + 5][sr] = a1.y * xscale;
      As[sq + 6][sr] = a1.z * xscale; As[sq + 7][sr] = a1.w * xscale;
      Bsh[sq + 0][sr] = b0.x; Bsh[sq + 1][sr] = b0.y;
      Bsh[sq + 2][sr] = b0.z; Bsh[sq + 3][sr] = b0.w;
      Bsh[sq + 4][sr] = b1.x; Bsh[sq + 5][sr] = b1.y;
      Bsh[sq + 6][sr] = b1.z; Bsh[sq + 7][sr] = b1.w;
      __syncthreads();
      #pragma unroll
      for (int d = 0; d < BKD; ++d) {
        float av[8], bv[8];
        float4 t;
        t = *(float4*)&As[d][tr * 4];       av[0]=t.x; av[1]=t.y; av[2]=t.z; av[3]=t.w;
        t = *(float4*)&As[d][64 + tr * 4];  av[4]=t.x; av[5]=t.y; av[6]=t.z; av[7]=t.w;
        t = *(float4*)&Bsh[d][tc * 4];      bv[0]=t.x; bv[1]=t.y; bv[2]=t.z; bv[3]=t.w;
        t = *(float4*)&Bsh[d][64 + tc * 4]; bv[4]=t.x; bv[5]=t.y; bv[6]=t.z; bv[7]=t.w;
        #pragma unroll
        for (int ri = 0; ri < 8; ++ri)
          #pragma unroll
          for (int cj = 0; cj < 8; ++cj)
            acc[ri][cj] += av[ri] * bv[cj];
      }
    }

    #pragma unroll
    for (int p = 0; p < 2; ++p) {
      __syncthreads();
      #pragma unroll
      for (int j = 0; j < 4; ++j) {
        int cl = tc * 4 + j;
        int cj = p * 4 + j;
        *(float4*)&Dump[cl * BM + tr * 4] =
            float4{acc[0][cj], acc[1][cj], acc[2][cj], acc[3][cj]};
        *(float4*)&Dump[cl * BM + 64 + tr * 4] =
            float4{acc[4][cj], acc[5][cj], acc[6][cj], acc[7][cj]};
      }
      __syncthreads();
      int kbase = col0 + kt * BN + p * 64 + sch * 32;
      #pragma unroll
      for (int cc = 0; cc < 32; ++cc) {
        float cv = Dump[(sch * 32 + cc) * BM + scr];
        int ck = kbase + cc;
        CAS_INS(tv0, tk0);
        CAS_INS(tv1, tk1);
        CAS_INS(tv2, tk2);
        CAS_INS(tv3, tk3);
      }
    }
  }

  int slot = split * 2 + sch;
  size_t cb = (size_t)(row0 + scr) * 16 + slot * 4;
  candv[cb + 0] = tv0; candv[cb + 1] = tv1;
  candv[cb + 2] = tv2; candv[cb + 3] = tv3;
  candi[cb + 0] = tk0; candi[cb + 1] = tk1;
  candi[cb + 2] = tk2; candi[cb + 3] = tk3;
}

__global__ __launch_bounds__(256) void refine_kernel(
    const float* __restrict__ x, const float* __restrict__ emb,
    const float* __restrict__ wn, const float* __restrict__ wnorm2,
    const float* __restrict__ candv, const int* __restrict__ candi,
    float* __restrict__ out, double* __restrict__ lossacc) {
  __shared__ float xbuf[4][512];
  __shared__ float wbuf8[4][8 * WSTR];
  int w = threadIdx.x >> 6, l = threadIdx.x & 63;
  int row = blockIdx.x * 4 + w;

  const float* xr = x + (size_t)row * DIMS + l * 8;
  float4 x0 = *(const float4*)xr;
  float4 x1 = *(const float4*)(xr + 4);
  *(float4*)&xbuf[w][l * 8]     = x0;
  *(float4*)&xbuf[w][l * 8 + 4] = x1;
  __syncthreads();
  float Sx = np_pairwise_sumsq_512(xbuf[w], l);
  float denx = fmaxf(__fsqrt_rn(Sx), 1e-12f);
  float xn[8];
  xn[0] = __fdiv_rn(x0.x, denx); xn[1] = __fdiv_rn(x0.y, denx);
  xn[2] = __fdiv_rn(x0.z, denx); xn[3] = __fdiv_rn(x0.w, denx);
  xn[4] = __fdiv_rn(x1.x, denx); xn[5] = __fdiv_rn(x1.y, denx);
  xn[6] = __fdiv_rn(x1.z, denx); xn[7] = __fdiv_rn(x1.w, denx);
  __syncthreads();
  *(float4*)&xbuf[w][l * 8]     = float4{xn[0], xn[1], xn[2], xn[3]};
  *(float4*)&xbuf[w][l * 8 + 4] = float4{xn[4], xn[5], xn[6], xn[7]};
  __syncthreads();
  float xn2 = np_pairwise_sumsq_512(xbuf[w], l);

  float cv = -INFINITY; int ck = 0x7fffffff;
  if (l < 16) { cv = candv[(size_t)row * 16 + l]; ck = candi[(size_t)row * 16 + l]; }
  int k8[8];
  #pragma unroll
  for (int it = 0; it < 8; ++it) {
    float mv = cv; int mk = ck;
    #pragma unroll
    for (int off = 1; off < 64; off <<= 1) {
      float ov = __shfl_xor(mv, off, 64);
      int ok = __shfl_xor(mk, off, 64);
      bool take = (ov > mv) || (ov == mv && ok < mk);
      mv = take ? ov : mv; mk = take ? ok : mk;
    }
    k8[it] = mk;
    if (ck == mk) cv = -INFINITY;
  }

  #pragma unroll
  for (int it = 0; it < 8; ++it) {
    const float* wr = wn + (size_t)k8[it] * DIMS + l * 8;
    float4 a = *(const float4*)wr;
    float4 b = *(const float4*)(wr + 4);
    *(float4*)&wbuf8[w][it * WSTR + l * 8]     = a;
    *(float4*)&wbuf8[w][it * WSTR + l * 8 + 4] = b;
  }
  __syncthreads();

  {
    int j = l & 7;
    const float* xp = xbuf[w];
    const float* wp = &wbuf8[w][j * WSTR];
    float t = 0.f;
    #pragma unroll 8
    for (int d = 0; d < 512; ++d) t = fmaf(xp[d], wp[d], t);

    float d8[8];
    #pragma unroll
    for (int it = 0; it < 8; ++it) {
      float dot = __shfl(t, it, 64);
      float s = __fadd_rn(xn2, wnorm2[k8[it]]);
      d8[it] = __fadd_rn(s, -(2.0f * dot));
    }

    float bd[3]; int bk[3];
    #pragma unroll
    for (int s = 0; s < 3; ++s) {
      float mv = INFINITY; int mk = 0x7fffffff;
      #pragma unroll
      for (int it = 0; it < 8; ++it) {
        bool take = (d8[it] < mv) || (d8[it] == mv && k8[it] < mk);
        mv = take ? d8[it] : mv; mk = take ? k8[it] : mk;
      }
      bd[s] = mv; bk[s] = mk;
      #pragma unroll
      for (int it = 0; it < 8; ++it)
        if (k8[it] == mk) d8[it] = INFINITY;
    }

    double i0 = 1.0 / (double)bd[0], i1 = 1.0 / (double)bd[1],
           i2 = 1.0 / (double)bd[2];
    double tot = (i0 + i1) + i2;
    double w0q = i0 / tot, w1q = i1 / tot, w2q = i2 / tot;

    if (l == 0) {
      float* oi = out + (size_t)N_ROWS * DIMS + 1 + (size_t)row * 3;
      oi[0] = (float)bk[0]; oi[1] = (float)bk[1]; oi[2] = (float)bk[2];
    }

    const float* e0 = emb + (size_t)bk[0] * DIMS + l * 8;
    const float* e1 = emb + (size_t)bk[1] * DIMS + l * 8;
    const float* e2 = emb + (size_t)bk[2] * DIMS + l * 8;
    float4 ea0 = *(const float4*)e0, eb0 = *(const float4*)(e0 + 4);
    float4 ea1 = *(const float4*)e1, eb1 = *(const float4*)(e1 + 4);
    float4 ea2 = *(const float4*)e2, eb2 = *(const float4*)(e2 + 4);
    double xs[8];
    xs[0] = x0.x; xs[1] = x0.y; xs[2] = x0.z; xs[3] = x0.w;
    xs[4] = x1.x; xs[5] = x1.y; xs[6] = x1.z; xs[7] = x1.w;
    double q[8];
    q[0] = w0q*(double)ea0.x + w1q*(double)ea1.x + w2q*(double)ea2.x;
    q[1] = w0q*(double)ea0.y + w1q*(double)ea1.y + w2q*(double)ea2.y;
    q[2] = w0q*(double)ea0.z + w1q*(double)ea1.z + w2q*(double)ea2.z;
    q[3] = w0q*(double)ea0.w + w1q*(double)ea1.w + w2q*(double)ea2.w;
    q[4] = w0q*(double)eb0.x + w1q*(double)eb1.x + w2q*(double)eb2.x;
    q[5] = w0q*(double)eb0.y + w1q*(double)eb1.y + w2q*(double)eb2.y;
    q[6] = w0q*(double)eb0.z + w1q*(double)eb1.z + w2q*(double)eb2.z;
    q[7] = w0q*(double)eb0.w + w1q*(double)eb1.w + w2q*(double)eb2.w;

    double lp = 0.0;
    float o[8];
    #pragma unroll
    for (int jj = 0; jj < 8; ++jj) {
      double diff = q[jj] - xs[jj];
      o[jj] = (float)(xs[jj] + diff);
      lp += diff * diff;
    }
    float* orow = out + (size_t)row * DIMS + l * 8;
    *(float4*)orow       = float4{o[0], o[1], o[2], o[3]};
    *(float4*)(orow + 4) = float4{o[4], o[5], o[6], o[7]};

    #pragma unroll
    for (int off = 1; off < 64; off <<= 1) lp += __shfl_xor(lp, off, 64);
    if (l == 0) atomicAdd(lossacc, lp);
  }
}

__global__ void loss_finalize_kernel(const double* __restrict__ lossacc,
                                     float* __restrict__ out) {
  double m = lossacc[0] / 16777216.0;   // N*D = 2^24, exact
  out[(size_t)N_ROWS * DIMS] = (float)(m + 0.25 * m);
}

// ---------------------------------------------------------------------------
extern "C" void kernel_launch(void* const* d_in, const int* in_sizes, int n_in,
                              void* d_out, int out_size, void* d_ws, size_t ws_size,
                              hipStream_t stream) {
  (void)in_sizes; (void)n_in; (void)out_size;
  const float* x   = (const float*)d_in[0];
  const float* emb = (const float*)d_in[1];
  float* out = (float*)d_out;
  char* ws = (char*)d_ws;

  if (ws_size >= 27426824) {
    // ---- MFMA path ----
    float*          wn      = (float*)(ws);                  // 16777216
    float*          wnorm2  = (float*)(ws + 16777216);       // 32768
    float*          xninv   = (float*)(ws + 16809984);       // 131072
    unsigned short* wnh     = (unsigned short*)(ws + 16941056); // 8388608
    unsigned*       candk   = (unsigned*)(ws + 25329664);    // 2097152
    double*         lossacc = (double*)(ws + 27426816);      // 8

    prep_w_np_kernel<<<K_CODES / 4, 256, 0, stream>>>(emb, wn, wnorm2, wnh);
    prep_x_kernel<<<N_ROWS / 4, 256, 0, stream>>>(x, xninv);
    mfma_topk_kernel<<<512, 256, 0, stream>>>(x, wnh, xninv, candk);
    hipMemsetAsync(lossacc, 0, 8, stream);
    refine_mfma_kernel<<<N_ROWS / 4, 256, 0, stream>>>(
        x, emb, wn, wnorm2, candk, out, lossacc);
    loss_finalize_kernel<<<1, 1, 0, stream>>>(lossacc, out);
  } else {
    // ---- fallback fp32 path (round-4, known-passing) ----
    float*  wn      = (float*)(ws);
    float*  wnorm2  = (float*)(ws + 16777216);
    float*  xninv   = (float*)(ws + 16809984);
    float*  candv   = (float*)(ws + 16941056);
    int*    candi   = (int*)  (ws + 19038208);
    double* lossacc = (double*)(ws + 21135360);

    prep_w_np_kernel<<<K_CODES / 4, 256, 0, stream>>>(emb, wn, wnorm2, nullptr);
    prep_x_kernel<<<N_ROWS / 4, 256, 0, stream>>>(x, xninv);
    gemm_topk_kernel<<<dim3(SPLITS, N_ROWS / BM), 256, 0, stream>>>(
        x, wn, xninv, candv, candi);
    hipMemsetAsync(lossacc, 0, 8, stream);
    refine_kernel<<<N_ROWS / 4, 256, 0, stream>>>(
        x, emb, wn, wnorm2, candv, candi, out, lossacc);
    loss_finalize_kernel<<<1, 1, 0, stream>>>(lossacc, out);
  }
}